// Round 1
// baseline (202.062 us; speedup 1.0000x reference)
//
#include <hip/hip_runtime.h>
#include <math.h>

#define DT   0.1f
#define HDT  0.005f
#define T_HIST 20
#define LEN_PRED 30

typedef __attribute__((ext_vector_type(8))) short bfrag8;   // 8 bf16 = 4 VGPRs
typedef __attribute__((ext_vector_type(4))) short short4v;  // 8 bytes
typedef __attribute__((ext_vector_type(4))) float f32x4;

// d_ws layout (bytes)
#define WS_FRAG   0u        // 96 frags * 512 bf16 * 2B = 98304
#define WS_WIN    98304u    // 2 frags * 1024B
#define WS_WOUT   100352u   // 1 frag * 1024B
#define WS_BIAS   101376u   // 2*3*128 floats = 3072B
#define WS_WINB   104448u   // 32 floats
#define WS_WOUTB  104576u   // 4 floats

static __device__ __forceinline__ unsigned short f2bf(float x) {
    union { float f; unsigned int u; } v; v.f = x;
    unsigned int r = v.u + 0x7fffu + ((v.u >> 16) & 1u);   // RNE
    return (unsigned short)(r >> 16);
}

// ---------------- weight prep: swizzle into MFMA A-frag order ----------------
__global__ void prep_kernel(const float* __restrict__ Win_W, const float* __restrict__ Win_b,
                            const float* __restrict__ eWih, const float* __restrict__ eWhh,
                            const float* __restrict__ ebih, const float* __restrict__ ebhh,
                            const float* __restrict__ dWih, const float* __restrict__ dWhh,
                            const float* __restrict__ dbih, const float* __restrict__ dbhh,
                            const float* __restrict__ Wout_W, const float* __restrict__ Wout_b,
                            char* __restrict__ ws)
{
    int i = blockIdx.x * blockDim.x + threadIdx.x;
    if (i < 49152) {
        // layer frags: fi = ((phase*3+l)*8 + g_t)*2 + c ; within = lane*8 + j
        int lin = i >> 9, within = i & 511;
        int lane = within >> 3, j = within & 7;
        int c = lin & 1, g_t = (lin >> 1) & 7;
        int pl = lin >> 4;                   // phase*3 + l
        int l = pl % 3, phase = pl / 3;
        int m = lane & 15, q2 = lane >> 4;
        int row = g_t * 16 + m, k = q2 * 8 + j;
        const float* W = (c == 0) ? (phase ? dWih : eWih) : (phase ? dWhh : eWhh);
        ((unsigned short*)(ws + WS_FRAG))[i] = f2bf(W[l * 4096 + row * 32 + k]);
    } else if (i < 50176) {
        int i2 = i - 49152;
        int wv = i2 >> 9, within = i2 & 511;
        int lane = within >> 3, j = within & 7;
        int m = lane & 15, q2 = lane >> 4;
        int row = wv * 16 + m, k = q2 * 8 + j;
        float v = (k < 24) ? Win_W[row * 24 + k] : 0.f;
        ((unsigned short*)(ws + WS_WIN))[i2] = f2bf(v);
    } else if (i < 50688) {
        int i3 = i - 50176;
        int lane = i3 >> 3, j = i3 & 7;
        int m = lane & 15, q2 = lane >> 4;
        int k = q2 * 8 + j;
        float v = (m < 4) ? Wout_W[m * 32 + k] : 0.f;
        ((unsigned short*)(ws + WS_WOUT))[i3] = f2bf(v);
    } else if (i < 51456) {
        int b = i - 50688;                    // 768 combined biases
        int phase = b / 384, rem = b % 384;
        int l = rem / 128, row = rem % 128;
        const float* bi = phase ? dbih : ebih;
        const float* bh = phase ? dbhh : ebhh;
        ((float*)(ws + WS_BIAS))[b] = bi[l * 128 + row] + bh[l * 128 + row];
    } else if (i < 51488) {
        int b = i - 51456;
        ((float*)(ws + WS_WINB))[b] = Win_b[b];
    } else if (i < 51492) {
        int b = i - 51488;
        ((float*)(ws + WS_WOUTB))[b] = Wout_b[b];
    }
}

// ---------------- main persistent kernel: 16 elems / 2-wave block ----------------
__launch_bounds__(128, 1)
__global__ void kalman_lstm_kernel(const float* __restrict__ hist,
                                   const float* __restrict__ max_ax, const float* __restrict__ max_ay,
                                   const float* __restrict__ vstd, const float* __restrict__ astd,
                                   const float* __restrict__ Rx_, const float* __restrict__ Ry_,
                                   const float* __restrict__ Gx, const float* __restrict__ Gy,
                                   const char* __restrict__ ws, float* __restrict__ out)
{
    __shared__ __align__(16) unsigned short xp[16][40];        // XP, k 24..31 zero pad
    __shared__ __align__(16) unsigned short xin[4][16][40];    // layer inputs (x0, c0, c1, c2)
    __shared__ __align__(16) unsigned short hbuf[2][3][16][40];// double-buffered h
    __shared__ __align__(16) float bias_lds[2][3][128];

    const int tid = threadIdx.x;
    const int w = tid >> 6;          // wave id == Kalman channel (0=x, 1=y)
    const int lane = tid & 63;
    const int q = lane >> 4;
    const int m = lane & 15;         // elem col for B/D, gate-row-in-tile for A
    const int base = blockIdx.x * 16;
    const int b_elem = base + m;

    // ---- load weight frags into registers (persistent for whole kernel) ----
    bfrag8 fragL[2][3][4][2];
    const bfrag8* fragp = (const bfrag8*)(ws + WS_FRAG);
#pragma unroll
    for (int ph = 0; ph < 2; ++ph)
#pragma unroll
        for (int l = 0; l < 3; ++l)
#pragma unroll
            for (int kd = 0; kd < 4; ++kd)
#pragma unroll
                for (int c = 0; c < 2; ++c) {
                    int g_t = w + 2 * kd;
                    int fi = ((ph * 3 + l) * 8 + g_t) * 2 + c;
                    fragL[ph][l][kd][c] = fragp[fi * 64 + lane];
                }
    bfrag8 winF  = ((const bfrag8*)(ws + WS_WIN))[w * 64 + lane];
    bfrag8 woutF = ((const bfrag8*)(ws + WS_WOUT))[lane];
    f32x4 winB   = *(const f32x4*)(ws + WS_WINB + (unsigned)((w * 16 + q * 4) * 4));
    f32x4 woutB  = *(const f32x4*)(ws + WS_WOUTB);

    // ---- cooperative LDS init ----
    for (int idx = tid; idx < 768; idx += 128)
        ((float*)bias_lds)[idx] = ((const float*)(ws + WS_BIAS))[idx];
    for (int idx = tid; idx < 16 * 40; idx += 128) (&xp[0][0])[idx] = 0;
    for (int idx = tid; idx < 4 * 16 * 40; idx += 128) (&xin[0][0][0])[idx] = 0;
    for (int idx = tid; idx < 2 * 3 * 16 * 40; idx += 128) (&hbuf[0][0][0][0])[idx] = 0;

    // ---- Kalman init (fp32, per-lane; lanes q==0 are authoritative) ----
    const float rx = Rx_[0] * Rx_[0], ry = Ry_[0] * Ry_[0];
    const float Rch = w ? ry : rx;
    const float v2 = vstd[0] * vstd[0], a2 = astd[0] * astd[0];
    float g0, g1, g2, ge0, ge1, ge2;
    if (w == 0) { g0 = Gx[0]; g1 = Gx[1]; g2 = Gx[2]; float s = max_ax[0]; ge0 = g0*s; ge1 = g1*s; ge2 = g2*s; }
    else        { g0 = Gy[0]; g1 = Gy[1]; g2 = Gy[2]; float s = max_ay[0]; ge0 = g0*s; ge1 = g1*s; ge2 = g2*s; }

    float X0 = hist[b_elem * (T_HIST * 2) + w], X1 = 0.f, X2 = 0.f;
    float P00 = rx, P01 = 0.f, P02 = 0.f, P11 = v2, P12 = 0.f, P22 = a2;

    float creg[3][4];
#pragma unroll
    for (int l = 0; l < 3; ++l)
#pragma unroll
        for (int r = 0; r < 4; ++r) creg[l][r] = 0.f;

    auto write_xp = [&]() {
        if (q == 0) {
            int o = w * 3;
            xp[m][o + 0] = f2bf(X0); xp[m][o + 1] = f2bf(X1); xp[m][o + 2] = f2bf(X2);
            int pb = 6 + w * 9;
            xp[m][pb + 0] = f2bf(P00); xp[m][pb + 1] = f2bf(P01); xp[m][pb + 2] = f2bf(P02);
            xp[m][pb + 3] = f2bf(P01); xp[m][pb + 4] = f2bf(P11); xp[m][pb + 5] = f2bf(P12);
            xp[m][pb + 6] = f2bf(P02); xp[m][pb + 7] = f2bf(P12); xp[m][pb + 8] = f2bf(P22);
        }
    };

    auto sig = [](float z) { return __builtin_amdgcn_rcpf(1.f + __expf(-z)); };
    auto th  = [](float z) { return fmaf(-2.f, __builtin_amdgcn_rcpf(__expf(2.f * z) + 1.f), 1.f); };

    auto kpred = [&](float Q00, float Q01, float Q02, float Q11, float Q12, float Q22) {
        X0 = X0 + DT * X1 + HDT * X2;
        X1 = X1 + DT * X2;
        float M00 = P00 + DT * P01 + HDT * P02;
        float M01 = P01 + DT * P11 + HDT * P12;
        float M02 = P02 + DT * P12 + HDT * P22;
        float M11 = P11 + DT * P12;
        float M12 = P12 + DT * P22;
        float M22 = P22;
        P00 = M00 + DT * M01 + HDT * M02 + Q00;
        P01 = M01 + DT * M02 + Q01;
        P02 = M02 + Q02;
        P11 = M11 + DT * M12 + Q11;
        P12 = M12 + Q12;
        P22 = M22 + Q22;
    };

    const f32x4 zero4 = {0.f, 0.f, 0.f, 0.f};

    // one LSTM-stack step; ph must be a literal at call site so fragL[ph] folds
    auto stack = [&](int ph, int p) {
        // Win: x0 = tanh(XP @ Win^T + b)
        bfrag8 bxp = *(const bfrag8*)&xp[m][q * 8];
        f32x4 aw = __builtin_amdgcn_mfma_f32_16x16x32_bf16(winF, bxp, zero4, 0, 0, 0);
        {
            union { short4v v; unsigned short s[4]; } u;
#pragma unroll
            for (int r = 0; r < 4; ++r) u.s[r] = f2bf(th(aw[r] + winB[r]));
            *(short4v*)&xin[0][m][w * 16 + q * 4] = u.v;
        }
        __syncthreads();
#pragma unroll
        for (int l = 0; l < 3; ++l) {
            bfrag8 bx = *(const bfrag8*)&xin[l][m][q * 8];
            bfrag8 bh = *(const bfrag8*)&hbuf[p][l][m][q * 8];
            f32x4 acc[4];
#pragma unroll
            for (int kd = 0; kd < 4; ++kd) {
                f32x4 t0 = __builtin_amdgcn_mfma_f32_16x16x32_bf16(fragL[ph][l][kd][0], bx, zero4, 0, 0, 0);
                acc[kd]  = __builtin_amdgcn_mfma_f32_16x16x32_bf16(fragL[ph][l][kd][1], bh, t0, 0, 0, 0);
            }
            f32x4 bb[4];
#pragma unroll
            for (int kd = 0; kd < 4; ++kd)
                bb[kd] = *(const f32x4*)&bias_lds[ph][l][16 * (w + 2 * kd) + 4 * q];
            union { short4v v; unsigned short s[4]; } hc, cc;
#pragma unroll
            for (int r = 0; r < 4; ++r) {
                float iv = sig(acc[0][r] + bb[0][r]);
                float fv = sig(acc[1][r] + bb[1][r]);
                float gv = th (acc[2][r] + bb[2][r]);
                float ov = sig(acc[3][r] + bb[3][r]);
                float cn = fmaf(fv, creg[l][r], iv * gv);
                float hn = ov * th(cn);
                creg[l][r] = cn;
                hc.s[r] = f2bf(hn);
                cc.s[r] = f2bf(cn);
            }
            *(short4v*)&hbuf[p ^ 1][l][m][w * 16 + q * 4] = hc.v;
            *(short4v*)&xin[l + 1][m][w * 16 + q * 4] = cc.v;
            __syncthreads();
        }
    };

    __syncthreads();     // LDS zero-fill visible
    write_xp();          // initial XP from kinit state
    int parity = 0;

    // ---------------- encoder: 19 steps ----------------
    for (int t = 0; t < T_HIST - 1; ++t) {
        __syncthreads();                                  // XP/h writes visible
        float z = hist[b_elem * (T_HIST * 2) + (t + 1) * 2 + w];
        stack(0, parity);
        kpred(ge0 * ge0, ge0 * ge1, ge0 * ge2, ge1 * ge1, ge1 * ge2, ge2 * ge2);
        // kupdate
        float y = z - X0;
        float S = P00 + Rch;
        float Sinv = 1.0f / S;
        float K0 = P00 * Sinv, K1 = P01 * Sinv, K2 = P02 * Sinv;
        X0 += y * K0; X1 += y * K1; X2 += y * K2;
        float p00 = P00, p01 = P01, p02 = P02;
        P00 = p00 - K0 * p00;
        P01 = p01 - K0 * p01;
        P02 = p02 - K0 * p02;
        P11 = P11 - K1 * p01;
        P12 = P12 - K1 * p02;
        P22 = P22 - K2 * p02;
        write_xp();
        parity ^= 1;
    }

    // ---------------- decoder: 30 steps ----------------
    for (int t = 0; t < LEN_PRED; ++t) {
        __syncthreads();
        stack(1, parity);
        // pred = c2 @ Wout^T + b (both waves compute; valid on q==0 lanes)
        bfrag8 bc2 = *(const bfrag8*)&xin[3][m][q * 8];
        f32x4 ap = __builtin_amdgcn_mfma_f32_16x16x32_bf16(woutF, bc2, zero4, 0, 0, 0);
        float pe = (w == 0) ? (ap[0] + woutB[0]) : (ap[1] + woutB[1]);
        float qe = (w == 0) ? (ap[2] + woutB[2]) : (ap[3] + woutB[3]);
        X2 = DT * pe;
        float qs = qe * qe;
        kpred(qs * g0 * g0, qs * g0 * g1, qs * g0 * g2, qs * g1 * g1, qs * g1 * g2, qs * g2 * g2);
        if (q == 0) {
            float* o = out + (size_t)b_elem * (LEN_PRED * 5) + t * 5;
            if (w == 0) { o[0] = X0; o[2] = sqrtf(P00); }
            else        { o[1] = X0; o[3] = sqrtf(P00); o[4] = 0.f; }
        }
        write_xp();
        parity ^= 1;
    }
}

extern "C" void kernel_launch(void* const* d_in, const int* in_sizes, int n_in,
                              void* d_out, int out_size, void* d_ws, size_t ws_size,
                              hipStream_t stream)
{
    const float* hist  = (const float*)d_in[0];
    const float* maxax = (const float*)d_in[1];
    const float* maxay = (const float*)d_in[2];
    const float* vstd  = (const float*)d_in[3];
    const float* astd  = (const float*)d_in[4];
    const float* Rx    = (const float*)d_in[5];
    const float* Ry    = (const float*)d_in[6];
    const float* Gx    = (const float*)d_in[7];
    const float* Gy    = (const float*)d_in[8];
    const float* WinW  = (const float*)d_in[9];
    const float* Winb  = (const float*)d_in[10];
    const float* eWih  = (const float*)d_in[11];
    const float* eWhh  = (const float*)d_in[12];
    const float* ebih  = (const float*)d_in[13];
    const float* ebhh  = (const float*)d_in[14];
    const float* dWih  = (const float*)d_in[15];
    const float* dWhh  = (const float*)d_in[16];
    const float* dbih  = (const float*)d_in[17];
    const float* dbhh  = (const float*)d_in[18];
    const float* WoutW = (const float*)d_in[19];
    const float* Woutb = (const float*)d_in[20];
    char* ws = (char*)d_ws;
    float* out = (float*)d_out;

    prep_kernel<<<202, 256, 0, stream>>>(WinW, Winb, eWih, eWhh, ebih, ebhh,
                                         dWih, dWhh, dbih, dbhh, WoutW, Woutb, ws);
    kalman_lstm_kernel<<<512, 128, 0, stream>>>(hist, maxax, maxay, vstd, astd,
                                                Rx, Ry, Gx, Gy, ws, out);
}